// Round 5
// baseline (228.046 us; speedup 1.0000x reference)
//
#include <hip/hip_runtime.h>
#include <hip/hip_bf16.h>

// OneStep: out = W - c * K^T (K W - V),  c = 0.2/(CTX*D) = 9.5367431640625e-8
// W:(4096,4096) K:(512,4096) V:(512,4096) fp32 -> out (4096,4096) fp32.
// bf16 MFMA w/ fp32 acc => absmax 2.441e-4 = 1 bf16 ulp (threshold 1.69e-3).
//
// R10 post-mortem: k1 58.5us -- traffic cut worked (FETCH 45->35MB) but
// 4 waves/CU (wave-private 96KB staging) collapsed streaming to 6.9 TB/s.
// Empirical law across m97/8-phase/R7: GEMM structures sustain ~12-14 TB/s
// aggregate CU<-L2 (~20 B/cyc/CU) and need ~8 waves/CU to do it.
// R11: k1 = 512-thread 8-wave BM=128 x BN=64, BK=64, block-SHARED 2-phase
// dbuf staging (k2's proven structure): 403 MB at 8 waves/CU; each wave owns
// a 32x32 output for the FULL K -> no cross-wave reduction, no reduce
// buffer; direct Rt = acc - Vt epilogue. Frag-ordered staging (24 units of
// 16rows x 64B per K-step, 3 gld16/thread), LDS reads lane-linear 16B.

typedef __bf16 bf16_t;
typedef __bf16 bf16x8 __attribute__((ext_vector_type(8)));
typedef float f32x4 __attribute__((ext_vector_type(4)));

#define D_DIM 4096
#define CTX_N 512
#define UPD_SCALE 9.5367431640625e-8f

__device__ __forceinline__ void gld16(const bf16_t* g, bf16_t* l) {
    __builtin_amdgcn_global_load_lds(
        (const __attribute__((address_space(1))) void*)g,
        (__attribute__((address_space(3))) void*)l, 16, 0, 0);
}

// ---- transpose+convert: src (M x N) fp32 tile -> dstT (N x M) bf16
//      [+ dstN (M x N) bf16].  64x64 tile at (bx,by); pad-65 (2-way = free).
__device__ __forceinline__ void t_body2(
    float* tile, const float* __restrict__ src, bf16_t* __restrict__ dstT,
    bf16_t* __restrict__ dstN, int M, int N, int bx, int by)
{
    const int tid = threadIdx.x;
    const int C0 = bx * 64, R0 = by * 64;
    const int r  = tid >> 2, cs = (tid & 3) * 16;

    const float* s = src + (size_t)(R0 + r) * N + C0 + cs;
    float f[16];
#pragma unroll
    for (int u = 0; u < 4; ++u) {
        const float4 v = ((const float4*)s)[u];
        f[4 * u + 0] = v.x; f[4 * u + 1] = v.y; f[4 * u + 2] = v.z; f[4 * u + 3] = v.w;
    }
#pragma unroll
    for (int u = 0; u < 16; ++u) tile[r * 65 + cs + u] = f[u];

    if (dstN) {
        bf16x8 v0, v1;
#pragma unroll
        for (int u = 0; u < 8; ++u) { v0[u] = (bf16_t)f[u]; v1[u] = (bf16_t)f[8 + u]; }
        bf16_t* d = dstN + (size_t)(R0 + r) * N + C0 + cs;
        *(bf16x8*)d = v0; *(bf16x8*)(d + 8) = v1;
    }
    __syncthreads();

    bf16x8 o0, o1;
#pragma unroll
    for (int u = 0; u < 8; ++u) {
        o0[u] = (bf16_t)tile[(cs + u) * 65 + r];
        o1[u] = (bf16_t)tile[(cs + 8 + u) * 65 + r];
    }
    bf16_t* d = dstT + (size_t)(C0 + r) * M + R0 + cs;
    *(bf16x8*)d = o0; *(bf16x8*)(d + 8) = o1;
}

// One launch for all three transposes: y<64 -> W, 64..71 -> K(+Kb), 72..79 -> V
__global__ __launch_bounds__(256) void t_all(
    const float* __restrict__ W, const float* __restrict__ K,
    const float* __restrict__ V, bf16_t* __restrict__ Wt,
    bf16_t* __restrict__ Kt, bf16_t* __restrict__ Kb, bf16_t* __restrict__ Vt)
{
    __shared__ float tile[64 * 65];
    const int y = blockIdx.y;
    if (y < 64)      t_body2(tile, W, Wt, nullptr, D_DIM, D_DIM, blockIdx.x, y);
    else if (y < 72) t_body2(tile, K, Kt, Kb,      CTX_N, D_DIM, blockIdx.x, y - 64);
    else             t_body2(tile, V, Vt, nullptr, CTX_N, D_DIM, blockIdx.x, y - 72);
}

// MFMA 16x16x32 bf16 (m89/m91): A/B frag: row=lane&15, k=quad*8+j (8 bf16);
// C/D: col=lane&15, row=quad*4+reg.  D[m][n] = sum_k A(m,k)*B(n,k).

// ---- K1: Rt[j][c] = sum_k Wt[j][k]*Kb[c][k] - Vt[j][c]  (4096 x 512) ----
// 512 threads (8 waves as 4m x 2n, each 32x32 out, acc[2][2]).
// 128(j) x 64(c) tile, BK=64, grid (32,8) = 256 blocks = 1/CU, 8 waves/CU.
// LDS/K-step: A = 16 units, B = 8 units; unit = 16 rows x 64B (1 KB), staged
// frag-ordered (lane l -> row l&15, colseg (l>>4)*8; LDS slot lane*16B).
// Wave w stages units {w, w+8, w+16} = 3 gld16/thread/step.
// 2-phase dbuf (2 x 24 KB): stage(t+1) before compute(t), one barrier/step.
// Default block id%8 XCD map: same bx (same Wt slice) -> same XCD L2.

__global__ __launch_bounds__(512, 2) void k1_residual(
    const bf16_t* __restrict__ Wt, const bf16_t* __restrict__ Kb,
    const bf16_t* __restrict__ Vt, bf16_t* __restrict__ Rt)
{
    __shared__ __align__(16) bf16_t stg[2 * 12288];  // 48 KB

    const int tid = threadIdx.x, wave = tid >> 6, lane = tid & 63;
    const int j0 = blockIdx.x * 128, c0 = blockIdx.y * 64;
    const int l15 = lane & 15, quad = lane >> 4;
    const int wm = wave >> 1, wn = wave & 1;       // wave's 32x32 output pos

    f32x4 acc[2][2] = {};

    // Staging roles for wave w: A(mi=w>>1, kk=w&1), A(mi=4+(w>>1), kk=w&1),
    // B(ni=w>>1, kk=w&1). Per-lane global base: row +l15, colseg +quad*8.
    const int smi = wave >> 1, skk = wave & 1;
    const bf16_t* gA1 = Wt + (size_t)(j0 + smi * 16 + l15) * D_DIM + skk * 32 + quad * 8;
    const bf16_t* gA2 = gA1 + (size_t)64 * D_DIM;
    const bf16_t* gB  = Kb + (size_t)(c0 + smi * 16 + l15) * D_DIM + skk * 32 + quad * 8;

    auto stage = [&](int bsel, int t) {
        bf16_t* base = stg + bsel * 12288;
        gld16(gA1 + t * 64, base + (size_t)wave * 512 + lane * 8);
        gld16(gA2 + t * 64, base + (size_t)(8 + wave) * 512 + lane * 8);
        gld16(gB  + t * 64, base + 8192 + (size_t)wave * 512 + lane * 8);
    };

#define K1_COMPUTE(BSEL)                                                     \
    {                                                                        \
        const bf16_t* buf = stg + (BSEL) * 12288;                            \
        bf16x8 a[2][2], b[2][2];                                             \
        _Pragma("unroll")                                                    \
        for (int kk = 0; kk < 2; ++kk)                                       \
            _Pragma("unroll")                                                \
            for (int x = 0; x < 2; ++x) {                                    \
                a[x][kk] = *(const bf16x8*)(                                 \
                    buf + ((wm * 2 + x) * 2 + kk) * 512 + lane * 8);         \
                b[x][kk] = *(const bf16x8*)(                                 \
                    buf + 8192 + ((wn * 2 + x) * 2 + kk) * 512 + lane * 8);  \
            }                                                                \
        _Pragma("unroll")                                                    \
        for (int kk = 0; kk < 2; ++kk)                                       \
            _Pragma("unroll")                                                \
            for (int mi = 0; mi < 2; ++mi)                                   \
                _Pragma("unroll")                                            \
                for (int ni = 0; ni < 2; ++ni)                               \
                    acc[mi][ni] = __builtin_amdgcn_mfma_f32_16x16x32_bf16(   \
                        a[mi][kk], b[ni][kk], acc[mi][ni], 0, 0, 0);         \
    }

    // 64 K-tiles of 64. Prologue: tile 0 -> buf0.
    stage(0, 0);
    __syncthreads();
#pragma unroll 1
    for (int t = 0; t < 62; t += 2) {
        stage(1, t + 1);
        __builtin_amdgcn_sched_barrier(0);
        K1_COMPUTE(0);                  // tile t
        __syncthreads();
        stage(0, t + 2);
        __builtin_amdgcn_sched_barrier(0);
        K1_COMPUTE(1);                  // tile t+1
        __syncthreads();
    }
    stage(1, 63);
    __builtin_amdgcn_sched_barrier(0);
    K1_COMPUTE(0);                      // tile 62
    __syncthreads();
    K1_COMPUTE(1);                      // tile 63

    // Direct epilogue: Rt = acc - Vt (no cross-wave reduction needed).
    // acc[mi][ni][r] -> row = j0+wm*32+mi*16+quad*4+r, col = c0+wn*32+ni*16+l15.
    {
        const size_t base =
            (size_t)(j0 + wm * 32 + quad * 4) * CTX_N + c0 + wn * 32 + l15;
#pragma unroll
        for (int mi = 0; mi < 2; ++mi)
#pragma unroll
            for (int r = 0; r < 4; ++r) {
                const size_t rowb = base + (size_t)(mi * 16 + r) * CTX_N;
#pragma unroll
                for (int ni = 0; ni < 2; ++ni) {
                    const size_t idx = rowb + ni * 16;
                    Rt[idx] = (bf16_t)(acc[mi][ni][r] - (float)Vt[idx]);
                }
            }
    }
}

// ---- K2: out[i][j] = W[i][j] - c * sum_c Kt[i][c]*Rt[j][c]  (4096x4096) ----
// 128x128 tile, BK=32, 4 waves of 64x64. Double-buffered staging (2x16 KB):
// stage(t+1) issued before compute(t), one __syncthreads per K-step.
// Epilogue is BARRIER-FREE: direct per-fragment W load (prefetched one
// mi-block ahead, statically indexed), FMA, dword store. Bijective XCD
// swizzle: 32 blocks sharing a Kt i-slice -> one XCD.

#define K2_COMPUTE(BSEL)                                                     \
    {                                                                        \
        const bf16_t* As = (const bf16_t*)(smem + (BSEL) * 16384);           \
        const bf16_t* Bs = (const bf16_t*)(smem + (BSEL) * 16384 + 8192);    \
        bf16x8 af[4], bq[4];                                                 \
        _Pragma("unroll")                                                    \
        for (int mi = 0; mi < 4; ++mi)                                       \
            af[mi] = *(const bf16x8*)(As + (wi + mi * 16 + l15) * 32 + quad * 8); \
        _Pragma("unroll")                                                    \
        for (int ni = 0; ni < 4; ++ni)                                       \
            bq[ni] = *(const bf16x8*)(Bs + (wj + ni * 16 + l15) * 32 + quad * 8); \
        _Pragma("unroll")                                                    \
        for (int mi = 0; mi < 4; ++mi)                                       \
            _Pragma("unroll")                                                \
            for (int ni = 0; ni < 4; ++ni)                                   \
                acc[mi][ni] = __builtin_amdgcn_mfma_f32_16x16x32_bf16(       \
                    af[mi], bq[ni], acc[mi][ni], 0, 0, 0);                   \
    }

__global__ __launch_bounds__(256) void k2_update(
    const bf16_t* __restrict__ Kt, const bf16_t* __restrict__ Rt,
    const float* __restrict__ W, float* __restrict__ out)
{
    __shared__ __align__(16) char smem[32768];  // buf0 16KB | buf1 16KB

    const int tid = threadIdx.x;

    // Bijective XCD swizzle: id = 8*xp + (yp&7) + 256*(yp>>3).
    // Same yp (same Kt i-slice) -> same id%8 -> same XCD L2.
    const int id = blockIdx.x + 32 * blockIdx.y;
    const int xp = (id >> 3) & 31;
    const int yp = (id & 7) + 8 * (id >> 8);
    const int j0 = xp * 128, i0 = yp * 128;

    const int lane = tid & 63, wave = tid >> 6;
    const int wi = (wave >> 1) * 64, wj = (wave & 1) * 64;
    const int l15 = lane & 15, quad = lane >> 4;

    f32x4 acc[4][4] = {};

    const bf16_t* ga = Kt + (size_t)(i0 + (tid >> 2)) * CTX_N + (tid & 3) * 8;
    const bf16_t* gb = Rt + (size_t)(j0 + (tid >> 2)) * CTX_N + (tid & 3) * 8;

    auto stage = [&](int bsel, int cc) {
        bf16_t* la = (bf16_t*)(smem + bsel * 16384) + tid * 8;
        bf16_t* lb = (bf16_t*)(smem + bsel * 16384 + 8192) + tid * 8;
        gld16(ga + cc, la);
        gld16(ga + cc + (size_t)64 * CTX_N, la + 64 * 32);
        gld16(gb + cc, lb);
        gld16(gb + cc + (size_t)64 * CTX_N, lb + 64 * 32);
    };

    // 16 K-tiles of 32. Prologue: tile 0 -> buf0.
    stage(0, 0);
    __syncthreads();
#pragma unroll 1
    for (int t = 1; t <= 13; t += 2) {
        stage(1, t * 32);
        __builtin_amdgcn_sched_barrier(0);
        K2_COMPUTE(0);                  // tile t-1
        __syncthreads();
        stage(0, (t + 1) * 32);
        __builtin_amdgcn_sched_barrier(0);
        K2_COMPUTE(1);                  // tile t
        __syncthreads();
    }
    stage(1, 15 * 32);
    __builtin_amdgcn_sched_barrier(0);
    K2_COMPUTE(0);                      // tile 14
    __syncthreads();
    K2_COMPUTE(1);                      // tile 15

    // ---- Barrier-free direct epilogue ----
    // acc[mi][ni][r] maps to row = i0+wi+mi*16+quad*4+r, col = j0+wj+ni*16+l15.
    const size_t base = (size_t)(i0 + wi + quad * 4) * D_DIM + j0 + wj + l15;
    const float* wp = W + base;
    float*       op = out + base;

    // Prefetch mi=0's 16 W fragments.
    float w0[16], w1[16];
#pragma unroll
    for (int r = 0; r < 4; ++r)
#pragma unroll
        for (int ni = 0; ni < 4; ++ni)
            w0[r * 4 + ni] = wp[(size_t)r * D_DIM + ni * 16];

#pragma unroll
    for (int mi = 0; mi < 4; ++mi) {
        float* wcur = (mi & 1) ? w1 : w0;
        float* wnxt = (mi & 1) ? w0 : w1;
        if (mi < 3) {
#pragma unroll
            for (int r = 0; r < 4; ++r)
#pragma unroll
                for (int ni = 0; ni < 4; ++ni)
                    wnxt[r * 4 + ni] =
                        wp[(size_t)((mi + 1) * 16 + r) * D_DIM + ni * 16];
        }
#pragma unroll
        for (int r = 0; r < 4; ++r)
#pragma unroll
            for (int ni = 0; ni < 4; ++ni)
                op[(size_t)(mi * 16 + r) * D_DIM + ni * 16] =
                    wcur[r * 4 + ni] - UPD_SCALE * acc[mi][ni][r];
    }
}

extern "C" void kernel_launch(void* const* d_in, const int* in_sizes, int n_in,
                              void* d_out, int out_size, void* d_ws, size_t ws_size,
                              hipStream_t stream) {
    const float* W = (const float*)d_in[0];   // (4096, 4096)
    const float* K = (const float*)d_in[1];   // (512, 4096)
    const float* V = (const float*)d_in[2];   // (512, 4096)
    float* out = (float*)d_out;

    char* ws = (char*)d_ws;                    // 48 MB used
    bf16_t* Wt = (bf16_t*)(ws);                            // (4096,4096) W^T
    bf16_t* Kt = (bf16_t*)(ws + (size_t)32 * 1024 * 1024); // (4096,512) K^T
    bf16_t* Kb = (bf16_t*)(ws + (size_t)36 * 1024 * 1024); // (512,4096) K
    bf16_t* Vt = (bf16_t*)(ws + (size_t)40 * 1024 * 1024); // (4096,512) V^T
    bf16_t* Rt = (bf16_t*)(ws + (size_t)44 * 1024 * 1024); // (4096,512) R^T

    t_all      <<<dim3(64, 80), 256, 0, stream>>>(W, K, V, Wt, Kt, Kb, Vt);
    k1_residual<<<dim3(32, 8),  512, 0, stream>>>(Wt, Kb, Vt, Rt);
    k2_update  <<<dim3(32, 32), 256, 0, stream>>>(Kt, Rt, W, out);
}

// Round 6
// 193.758 us; speedup vs baseline: 1.1770x; 1.1770x over previous
//
#include <hip/hip_runtime.h>
#include <hip/hip_bf16.h>

// OneStep: out = W - c * K^T (K W - V),  c = 0.2/(CTX*D) = 9.5367431640625e-8
// W:(4096,4096) K:(512,4096) V:(512,4096) fp32 -> out (4096,4096) fp32.
// bf16 MFMA w/ fp32 acc => absmax 2.441e-4 = 1 bf16 ulp (threshold 1.69e-3).
//
// R11 post-mortem: k1 68us. Streaming law from R7/R10/R11: rate scales with
// INDEPENDENT barrier groups per CU (2 groups -> 19 B/cyc, 1 group -> ~10),
// not wave count. R11's 8 lockstep waves = 1 stream.
// R12: k1 = (64,64) tile, grid 512 = 2 blocks/CU (two independent streams),
// 256 threads, k2's proven 2-phase dbuf barrier loop; BK=64 staging in
// 8-row x 128B units (half the request count of 16-row x 64B); slot-XOR
// swizzle via pre-permuted GLOBAL source (LDS dest stays lane-linear, rule
// for global_load_lds), frag reads apply the same XOR -> conflict-free b128.
// Full-K per wave (32x32 out each) -> no cross-wave reduction, direct
// Rt = acc - Vt epilogue.

typedef __bf16 bf16_t;
typedef __bf16 bf16x8 __attribute__((ext_vector_type(8)));
typedef float f32x4 __attribute__((ext_vector_type(4)));

#define D_DIM 4096
#define CTX_N 512
#define UPD_SCALE 9.5367431640625e-8f

__device__ __forceinline__ void gld16(const bf16_t* g, bf16_t* l) {
    __builtin_amdgcn_global_load_lds(
        (const __attribute__((address_space(1))) void*)g,
        (__attribute__((address_space(3))) void*)l, 16, 0, 0);
}

// ---- transpose+convert: src (M x N) fp32 tile -> dstT (N x M) bf16
//      [+ dstN (M x N) bf16].  64x64 tile at (bx,by); pad-65 (2-way = free).
__device__ __forceinline__ void t_body2(
    float* tile, const float* __restrict__ src, bf16_t* __restrict__ dstT,
    bf16_t* __restrict__ dstN, int M, int N, int bx, int by)
{
    const int tid = threadIdx.x;
    const int C0 = bx * 64, R0 = by * 64;
    const int r  = tid >> 2, cs = (tid & 3) * 16;

    const float* s = src + (size_t)(R0 + r) * N + C0 + cs;
    float f[16];
#pragma unroll
    for (int u = 0; u < 4; ++u) {
        const float4 v = ((const float4*)s)[u];
        f[4 * u + 0] = v.x; f[4 * u + 1] = v.y; f[4 * u + 2] = v.z; f[4 * u + 3] = v.w;
    }
#pragma unroll
    for (int u = 0; u < 16; ++u) tile[r * 65 + cs + u] = f[u];

    if (dstN) {
        bf16x8 v0, v1;
#pragma unroll
        for (int u = 0; u < 8; ++u) { v0[u] = (bf16_t)f[u]; v1[u] = (bf16_t)f[8 + u]; }
        bf16_t* d = dstN + (size_t)(R0 + r) * N + C0 + cs;
        *(bf16x8*)d = v0; *(bf16x8*)(d + 8) = v1;
    }
    __syncthreads();

    bf16x8 o0, o1;
#pragma unroll
    for (int u = 0; u < 8; ++u) {
        o0[u] = (bf16_t)tile[(cs + u) * 65 + r];
        o1[u] = (bf16_t)tile[(cs + 8 + u) * 65 + r];
    }
    bf16_t* d = dstT + (size_t)(C0 + r) * M + R0 + cs;
    *(bf16x8*)d = o0; *(bf16x8*)(d + 8) = o1;
}

// One launch for all three transposes: y<64 -> W, 64..71 -> K(+Kb), 72..79 -> V
__global__ __launch_bounds__(256) void t_all(
    const float* __restrict__ W, const float* __restrict__ K,
    const float* __restrict__ V, bf16_t* __restrict__ Wt,
    bf16_t* __restrict__ Kt, bf16_t* __restrict__ Kb, bf16_t* __restrict__ Vt)
{
    __shared__ float tile[64 * 65];
    const int y = blockIdx.y;
    if (y < 64)      t_body2(tile, W, Wt, nullptr, D_DIM, D_DIM, blockIdx.x, y);
    else if (y < 72) t_body2(tile, K, Kt, Kb,      CTX_N, D_DIM, blockIdx.x, y - 64);
    else             t_body2(tile, V, Vt, nullptr, CTX_N, D_DIM, blockIdx.x, y - 72);
}

// MFMA 16x16x32 bf16 (m89/m91): A/B frag: row=lane&15, k=quad*8+j (8 bf16);
// C/D: col=lane&15, row=quad*4+reg.  D[m][n] = sum_k A(m,k)*B(n,k).

// ---- K1: Rt[j][c] = sum_k Wt[j][k]*Kb[c][k] - Vt[j][c]  (4096 x 512) ----
// 64(j) x 64(c) tile, grid (64,8) = 512 blocks = 2/CU (two independent
// streams per CU). 256 threads, 4 waves as 2m x 2n, each 32x32 out
// (acc[2][2]), FULL K per wave -> no cross-wave reduction.
// BK=64: A/B tiles = 8 units each of (8 rows x 64 k) = 1 KB; staged with
// 128B-contiguous rows. Unit layout: slot s (16B) holds (row=s>>3,
// seg=(s&7)^(s>>3)); gld16 lane l sources global (row=l>>3, seg=(l&7)^(l>>3))
// so LDS dest stays lane-linear. Frag read slot = r3*8 + ((kk*4+quad)^r3):
// 8 disjoint 4-bank groups x 8 lanes = conflict-free b128.
// 2-phase dbuf (2 x 16 KB), stage(t+1) before compute(t), 1 barrier/step.
// XCD: id%8 = bx%8 -> the 8 c-sharers of a Wt j-slice land on one XCD.

__global__ __launch_bounds__(256, 2) void k1_residual(
    const bf16_t* __restrict__ Wt, const bf16_t* __restrict__ Kb,
    const bf16_t* __restrict__ Vt, bf16_t* __restrict__ Rt)
{
    __shared__ __align__(16) bf16_t stg[16384];  // 2 x (A 8KB + B 8KB)

    const int tid = threadIdx.x, wave = tid >> 6, lane = tid & 63;
    const int j0 = blockIdx.x * 64, c0 = blockIdx.y * 64;
    const int l15 = lane & 15, quad = lane >> 4;
    const int wm = wave >> 1, wn = wave & 1;   // wave's 32x32 output pos

    f32x4 acc[2][2] = {};

    // Staging source (pre-permuted for the slot-XOR layout):
    const int rl = lane >> 3;                  // row within unit 0..7
    const int sl = ((lane & 7) ^ rl) * 8;      // permuted 16B seg (elems)
    const bf16_t* gA0 = Wt + (size_t)(j0 + wave * 8      + rl) * D_DIM + sl;
    const bf16_t* gA1 = Wt + (size_t)(j0 + wave * 8 + 32 + rl) * D_DIM + sl;
    const bf16_t* gB0 = Kb + (size_t)(c0 + wave * 8      + rl) * D_DIM + sl;
    const bf16_t* gB1 = Kb + (size_t)(c0 + wave * 8 + 32 + rl) * D_DIM + sl;

    auto stage = [&](int bsel, int t) {
        bf16_t* buf = stg + bsel * 8192;
        gld16(gA0 + t * 64, buf + (size_t)wave * 512 + lane * 8);        // A unit wave
        gld16(gA1 + t * 64, buf + (size_t)(wave + 4) * 512 + lane * 8);  // A unit wave+4
        gld16(gB0 + t * 64, buf + 4096 + (size_t)wave * 512 + lane * 8); // B unit wave
        gld16(gB1 + t * 64, buf + 4096 + (size_t)(wave + 4) * 512 + lane * 8);
    };

#define K1_COMPUTE(BSEL)                                                     \
    {                                                                        \
        const bf16_t* buf = stg + (BSEL) * 8192;                             \
        const int r3 = l15 & 7, uh = l15 >> 3;                               \
        bf16x8 a[2][2], b[2][2];                                             \
        _Pragma("unroll")                                                    \
        for (int kk = 0; kk < 2; ++kk) {                                     \
            const int slot = r3 * 8 + ((kk * 4 + quad) ^ r3);                \
            _Pragma("unroll")                                                \
            for (int x = 0; x < 2; ++x) {                                    \
                const int uA = wm * 4 + x * 2 + uh;                          \
                const int uB = wn * 4 + x * 2 + uh;                          \
                a[x][kk] = *(const bf16x8*)(buf + uA * 512 + slot * 8);      \
                b[x][kk] = *(const bf16x8*)(buf + 4096 + uB * 512 + slot * 8); \
            }                                                                \
        }                                                                    \
        _Pragma("unroll")                                                    \
        for (int kk = 0; kk < 2; ++kk)                                       \
            _Pragma("unroll")                                                \
            for (int mi = 0; mi < 2; ++mi)                                   \
                _Pragma("unroll")                                            \
                for (int ni = 0; ni < 2; ++ni)                               \
                    acc[mi][ni] = __builtin_amdgcn_mfma_f32_16x16x32_bf16(   \
                        a[mi][kk], b[ni][kk], acc[mi][ni], 0, 0, 0);         \
    }

    // 64 K-tiles of 64. Prologue: tile 0 -> buf0.
    stage(0, 0);
    __syncthreads();
#pragma unroll 1
    for (int t = 0; t < 62; t += 2) {
        stage(1, t + 1);
        __builtin_amdgcn_sched_barrier(0);
        K1_COMPUTE(0);                  // tile t
        __syncthreads();
        stage(0, t + 2);
        __builtin_amdgcn_sched_barrier(0);
        K1_COMPUTE(1);                  // tile t+1
        __syncthreads();
    }
    stage(1, 63);
    __builtin_amdgcn_sched_barrier(0);
    K1_COMPUTE(0);                      // tile 62
    __syncthreads();
    K1_COMPUTE(1);                      // tile 63

    // Direct epilogue: Rt = acc - Vt.
    // acc[mi][ni][r] -> row = j0+wm*32+mi*16+quad*4+r, col = c0+wn*32+ni*16+l15.
    {
        const size_t base =
            (size_t)(j0 + wm * 32 + quad * 4) * CTX_N + c0 + wn * 32 + l15;
#pragma unroll
        for (int mi = 0; mi < 2; ++mi)
#pragma unroll
            for (int r = 0; r < 4; ++r) {
                const size_t rowb = base + (size_t)(mi * 16 + r) * CTX_N;
#pragma unroll
                for (int ni = 0; ni < 2; ++ni) {
                    const size_t idx = rowb + ni * 16;
                    Rt[idx] = (bf16_t)(acc[mi][ni][r] - (float)Vt[idx]);
                }
            }
    }
}

// ---- K2: out[i][j] = W[i][j] - c * sum_c Kt[i][c]*Rt[j][c]  (4096x4096) ----
// 128x128 tile, BK=32, 4 waves of 64x64. Double-buffered staging (2x16 KB):
// stage(t+1) issued before compute(t), one __syncthreads per K-step.
// Epilogue is BARRIER-FREE: direct per-fragment W load (prefetched one
// mi-block ahead, statically indexed), FMA, dword store. Bijective XCD
// swizzle: 32 blocks sharing a Kt i-slice -> one XCD.

#define K2_COMPUTE(BSEL)                                                     \
    {                                                                        \
        const bf16_t* As = (const bf16_t*)(smem + (BSEL) * 16384);           \
        const bf16_t* Bs = (const bf16_t*)(smem + (BSEL) * 16384 + 8192);    \
        bf16x8 af[4], bq[4];                                                 \
        _Pragma("unroll")                                                    \
        for (int mi = 0; mi < 4; ++mi)                                       \
            af[mi] = *(const bf16x8*)(As + (wi + mi * 16 + l15) * 32 + quad * 8); \
        _Pragma("unroll")                                                    \
        for (int ni = 0; ni < 4; ++ni)                                       \
            bq[ni] = *(const bf16x8*)(Bs + (wj + ni * 16 + l15) * 32 + quad * 8); \
        _Pragma("unroll")                                                    \
        for (int mi = 0; mi < 4; ++mi)                                       \
            _Pragma("unroll")                                                \
            for (int ni = 0; ni < 4; ++ni)                                   \
                acc[mi][ni] = __builtin_amdgcn_mfma_f32_16x16x32_bf16(       \
                    af[mi], bq[ni], acc[mi][ni], 0, 0, 0);                   \
    }

__global__ __launch_bounds__(256) void k2_update(
    const bf16_t* __restrict__ Kt, const bf16_t* __restrict__ Rt,
    const float* __restrict__ W, float* __restrict__ out)
{
    __shared__ __align__(16) char smem[32768];  // buf0 16KB | buf1 16KB

    const int tid = threadIdx.x;

    // Bijective XCD swizzle: id = 8*xp + (yp&7) + 256*(yp>>3).
    // Same yp (same Kt i-slice) -> same id%8 -> same XCD L2.
    const int id = blockIdx.x + 32 * blockIdx.y;
    const int xp = (id >> 3) & 31;
    const int yp = (id & 7) + 8 * (id >> 8);
    const int j0 = xp * 128, i0 = yp * 128;

    const int lane = tid & 63, wave = tid >> 6;
    const int wi = (wave >> 1) * 64, wj = (wave & 1) * 64;
    const int l15 = lane & 15, quad = lane >> 4;

    f32x4 acc[4][4] = {};

    const bf16_t* ga = Kt + (size_t)(i0 + (tid >> 2)) * CTX_N + (tid & 3) * 8;
    const bf16_t* gb = Rt + (size_t)(j0 + (tid >> 2)) * CTX_N + (tid & 3) * 8;

    auto stage = [&](int bsel, int cc) {
        bf16_t* la = (bf16_t*)(smem + bsel * 16384) + tid * 8;
        bf16_t* lb = (bf16_t*)(smem + bsel * 16384 + 8192) + tid * 8;
        gld16(ga + cc, la);
        gld16(ga + cc + (size_t)64 * CTX_N, la + 64 * 32);
        gld16(gb + cc, lb);
        gld16(gb + cc + (size_t)64 * CTX_N, lb + 64 * 32);
    };

    // 16 K-tiles of 32. Prologue: tile 0 -> buf0.
    stage(0, 0);
    __syncthreads();
#pragma unroll 1
    for (int t = 1; t <= 13; t += 2) {
        stage(1, t * 32);
        __builtin_amdgcn_sched_barrier(0);
        K2_COMPUTE(0);                  // tile t-1
        __syncthreads();
        stage(0, (t + 1) * 32);
        __builtin_amdgcn_sched_barrier(0);
        K2_COMPUTE(1);                  // tile t
        __syncthreads();
    }
    stage(1, 15 * 32);
    __builtin_amdgcn_sched_barrier(0);
    K2_COMPUTE(0);                      // tile 14
    __syncthreads();
    K2_COMPUTE(1);                      // tile 15

    // ---- Barrier-free direct epilogue ----
    // acc[mi][ni][r] maps to row = i0+wi+mi*16+quad*4+r, col = j0+wj+ni*16+l15.
    const size_t base = (size_t)(i0 + wi + quad * 4) * D_DIM + j0 + wj + l15;
    const float* wp = W + base;
    float*       op = out + base;

    // Prefetch mi=0's 16 W fragments.
    float w0[16], w1[16];
#pragma unroll
    for (int r = 0; r < 4; ++r)
#pragma unroll
        for (int ni = 0; ni < 4; ++ni)
            w0[r * 4 + ni] = wp[(size_t)r * D_DIM + ni * 16];

#pragma unroll
    for (int mi = 0; mi < 4; ++mi) {
        float* wcur = (mi & 1) ? w1 : w0;
        float* wnxt = (mi & 1) ? w0 : w1;
        if (mi < 3) {
#pragma unroll
            for (int r = 0; r < 4; ++r)
#pragma unroll
                for (int ni = 0; ni < 4; ++ni)
                    wnxt[r * 4 + ni] =
                        wp[(size_t)((mi + 1) * 16 + r) * D_DIM + ni * 16];
        }
#pragma unroll
        for (int r = 0; r < 4; ++r)
#pragma unroll
            for (int ni = 0; ni < 4; ++ni)
                op[(size_t)(mi * 16 + r) * D_DIM + ni * 16] =
                    wcur[r * 4 + ni] - UPD_SCALE * acc[mi][ni][r];
    }
}

extern "C" void kernel_launch(void* const* d_in, const int* in_sizes, int n_in,
                              void* d_out, int out_size, void* d_ws, size_t ws_size,
                              hipStream_t stream) {
    const float* W = (const float*)d_in[0];   // (4096, 4096)
    const float* K = (const float*)d_in[1];   // (512, 4096)
    const float* V = (const float*)d_in[2];   // (512, 4096)
    float* out = (float*)d_out;

    char* ws = (char*)d_ws;                    // 48 MB used
    bf16_t* Wt = (bf16_t*)(ws);                            // (4096,4096) W^T
    bf16_t* Kt = (bf16_t*)(ws + (size_t)32 * 1024 * 1024); // (4096,512) K^T
    bf16_t* Kb = (bf16_t*)(ws + (size_t)36 * 1024 * 1024); // (512,4096) K
    bf16_t* Vt = (bf16_t*)(ws + (size_t)40 * 1024 * 1024); // (4096,512) V^T
    bf16_t* Rt = (bf16_t*)(ws + (size_t)44 * 1024 * 1024); // (4096,512) R^T

    t_all      <<<dim3(64, 80), 256, 0, stream>>>(W, K, V, Wt, Kt, Kb, Vt);
    k1_residual<<<dim3(64, 8),  256, 0, stream>>>(Wt, Kb, Vt, Rt);
    k2_update  <<<dim3(32, 32), 256, 0, stream>>>(Kt, Rt, W, out);
}

// Round 7
// 192.998 us; speedup vs baseline: 1.1816x; 1.0039x over previous
//
#include <hip/hip_runtime.h>
#include <hip/hip_bf16.h>

// OneStep: out = W - c * K^T (K W - V),  c = 0.2/(CTX*D) = 9.5367431640625e-8
// W:(4096,4096) K:(512,4096) V:(512,4096) fp32 -> out (4096,4096) fp32.
// bf16 MFMA w/ fp32 acc => absmax 2.441e-4 = 1 bf16 ulp (threshold 1.69e-3).
//
// R12 post-mortem: total 194; k1 fixed (<=43, was 68) -- streaming law
// (independent barrier groups/CU) + slot-XOR staging confirmed. k2 now top
// at ~44us: K-loop 268 MB L2 @ ~12.8 TB/s (22us) + epilogue 128 MB HBM
// (21us), barely overlapped; plus 2^21 LDS bank-conflict cycles from
// stride-64B frag reads.
// R13: k2 = BM=256 x BN=128 (512 thr, 8 waves of 64x64 acc[4][4]), traffic
// 268->192 MB, grid (32,16)=512 blocks = 2/CU (2 streams, streaming law ok),
// LDS 48KB dbuf. Slot-XOR swizzle (R12's rule-21 pattern): global source seg
// pre-permuted, LDS dest lane-linear, frag read seg = quad^(row&3) -> <=2-way
// (free). Epilogue + XCD swizzle unchanged. k1/t_all untouched.

typedef __bf16 bf16_t;
typedef __bf16 bf16x8 __attribute__((ext_vector_type(8)));
typedef float f32x4 __attribute__((ext_vector_type(4)));

#define D_DIM 4096
#define CTX_N 512
#define UPD_SCALE 9.5367431640625e-8f

__device__ __forceinline__ void gld16(const bf16_t* g, bf16_t* l) {
    __builtin_amdgcn_global_load_lds(
        (const __attribute__((address_space(1))) void*)g,
        (__attribute__((address_space(3))) void*)l, 16, 0, 0);
}

// ---- transpose+convert: src (M x N) fp32 tile -> dstT (N x M) bf16
//      [+ dstN (M x N) bf16].  64x64 tile at (bx,by); pad-65 (2-way = free).
__device__ __forceinline__ void t_body2(
    float* tile, const float* __restrict__ src, bf16_t* __restrict__ dstT,
    bf16_t* __restrict__ dstN, int M, int N, int bx, int by)
{
    const int tid = threadIdx.x;
    const int C0 = bx * 64, R0 = by * 64;
    const int r  = tid >> 2, cs = (tid & 3) * 16;

    const float* s = src + (size_t)(R0 + r) * N + C0 + cs;
    float f[16];
#pragma unroll
    for (int u = 0; u < 4; ++u) {
        const float4 v = ((const float4*)s)[u];
        f[4 * u + 0] = v.x; f[4 * u + 1] = v.y; f[4 * u + 2] = v.z; f[4 * u + 3] = v.w;
    }
#pragma unroll
    for (int u = 0; u < 16; ++u) tile[r * 65 + cs + u] = f[u];

    if (dstN) {
        bf16x8 v0, v1;
#pragma unroll
        for (int u = 0; u < 8; ++u) { v0[u] = (bf16_t)f[u]; v1[u] = (bf16_t)f[8 + u]; }
        bf16_t* d = dstN + (size_t)(R0 + r) * N + C0 + cs;
        *(bf16x8*)d = v0; *(bf16x8*)(d + 8) = v1;
    }
    __syncthreads();

    bf16x8 o0, o1;
#pragma unroll
    for (int u = 0; u < 8; ++u) {
        o0[u] = (bf16_t)tile[(cs + u) * 65 + r];
        o1[u] = (bf16_t)tile[(cs + 8 + u) * 65 + r];
    }
    bf16_t* d = dstT + (size_t)(C0 + r) * M + R0 + cs;
    *(bf16x8*)d = o0; *(bf16x8*)(d + 8) = o1;
}

// One launch for all three transposes: y<64 -> W, 64..71 -> K(+Kb), 72..79 -> V
__global__ __launch_bounds__(256) void t_all(
    const float* __restrict__ W, const float* __restrict__ K,
    const float* __restrict__ V, bf16_t* __restrict__ Wt,
    bf16_t* __restrict__ Kt, bf16_t* __restrict__ Kb, bf16_t* __restrict__ Vt)
{
    __shared__ float tile[64 * 65];
    const int y = blockIdx.y;
    if (y < 64)      t_body2(tile, W, Wt, nullptr, D_DIM, D_DIM, blockIdx.x, y);
    else if (y < 72) t_body2(tile, K, Kt, Kb,      CTX_N, D_DIM, blockIdx.x, y - 64);
    else             t_body2(tile, V, Vt, nullptr, CTX_N, D_DIM, blockIdx.x, y - 72);
}

// MFMA 16x16x32 bf16 (m89/m91): A/B frag: row=lane&15, k=quad*8+j (8 bf16);
// C/D: col=lane&15, row=quad*4+reg.  D[m][n] = sum_k A(m,k)*B(n,k).

// ---- K1: Rt[j][c] = sum_k Wt[j][k]*Kb[c][k] - Vt[j][c]  (4096 x 512) ----
// 64(j) x 64(c) tile, grid (64,8) = 512 blocks = 2/CU (two independent
// streams per CU). 256 threads, 4 waves as 2m x 2n, each 32x32 out
// (acc[2][2]), FULL K per wave -> no cross-wave reduction.
// BK=64: A/B tiles = 8 units each of (8 rows x 64 k) = 1 KB; staged with
// 128B-contiguous rows. Unit layout: slot s (16B) holds (row=s>>3,
// seg=(s&7)^(s>>3)); gld16 lane l sources global (row=l>>3, seg=(l&7)^(l>>3))
// so LDS dest stays lane-linear. Frag read slot = r3*8 + ((kk*4+quad)^r3):
// conflict-free b128.
// 2-phase dbuf (2 x 16 KB), stage(t+1) before compute(t), 1 barrier/step.

__global__ __launch_bounds__(256, 2) void k1_residual(
    const bf16_t* __restrict__ Wt, const bf16_t* __restrict__ Kb,
    const bf16_t* __restrict__ Vt, bf16_t* __restrict__ Rt)
{
    __shared__ __align__(16) bf16_t stg[16384];  // 2 x (A 8KB + B 8KB)

    const int tid = threadIdx.x, wave = tid >> 6, lane = tid & 63;
    const int j0 = blockIdx.x * 64, c0 = blockIdx.y * 64;
    const int l15 = lane & 15, quad = lane >> 4;
    const int wm = wave >> 1, wn = wave & 1;   // wave's 32x32 output pos

    f32x4 acc[2][2] = {};

    // Staging source (pre-permuted for the slot-XOR layout):
    const int rl = lane >> 3;                  // row within unit 0..7
    const int sl = ((lane & 7) ^ rl) * 8;      // permuted 16B seg (elems)
    const bf16_t* gA0 = Wt + (size_t)(j0 + wave * 8      + rl) * D_DIM + sl;
    const bf16_t* gA1 = Wt + (size_t)(j0 + wave * 8 + 32 + rl) * D_DIM + sl;
    const bf16_t* gB0 = Kb + (size_t)(c0 + wave * 8      + rl) * D_DIM + sl;
    const bf16_t* gB1 = Kb + (size_t)(c0 + wave * 8 + 32 + rl) * D_DIM + sl;

    auto stage = [&](int bsel, int t) {
        bf16_t* buf = stg + bsel * 8192;
        gld16(gA0 + t * 64, buf + (size_t)wave * 512 + lane * 8);
        gld16(gA1 + t * 64, buf + (size_t)(wave + 4) * 512 + lane * 8);
        gld16(gB0 + t * 64, buf + 4096 + (size_t)wave * 512 + lane * 8);
        gld16(gB1 + t * 64, buf + 4096 + (size_t)(wave + 4) * 512 + lane * 8);
    };

#define K1_COMPUTE(BSEL)                                                     \
    {                                                                        \
        const bf16_t* buf = stg + (BSEL) * 8192;                             \
        const int r3 = l15 & 7, uh = l15 >> 3;                               \
        bf16x8 a[2][2], b[2][2];                                             \
        _Pragma("unroll")                                                    \
        for (int kk = 0; kk < 2; ++kk) {                                     \
            const int slot = r3 * 8 + ((kk * 4 + quad) ^ r3);                \
            _Pragma("unroll")                                                \
            for (int x = 0; x < 2; ++x) {                                    \
                const int uA = wm * 4 + x * 2 + uh;                          \
                const int uB = wn * 4 + x * 2 + uh;                          \
                a[x][kk] = *(const bf16x8*)(buf + uA * 512 + slot * 8);      \
                b[x][kk] = *(const bf16x8*)(buf + 4096 + uB * 512 + slot * 8); \
            }                                                                \
        }                                                                    \
        _Pragma("unroll")                                                    \
        for (int kk = 0; kk < 2; ++kk)                                       \
            _Pragma("unroll")                                                \
            for (int mi = 0; mi < 2; ++mi)                                   \
                _Pragma("unroll")                                            \
                for (int ni = 0; ni < 2; ++ni)                               \
                    acc[mi][ni] = __builtin_amdgcn_mfma_f32_16x16x32_bf16(   \
                        a[mi][kk], b[ni][kk], acc[mi][ni], 0, 0, 0);         \
    }

    // 64 K-tiles of 64. Prologue: tile 0 -> buf0.
    stage(0, 0);
    __syncthreads();
#pragma unroll 1
    for (int t = 0; t < 62; t += 2) {
        stage(1, t + 1);
        __builtin_amdgcn_sched_barrier(0);
        K1_COMPUTE(0);                  // tile t
        __syncthreads();
        stage(0, t + 2);
        __builtin_amdgcn_sched_barrier(0);
        K1_COMPUTE(1);                  // tile t+1
        __syncthreads();
    }
    stage(1, 63);
    __builtin_amdgcn_sched_barrier(0);
    K1_COMPUTE(0);                      // tile 62
    __syncthreads();
    K1_COMPUTE(1);                      // tile 63

    // Direct epilogue: Rt = acc - Vt.
    // acc[mi][ni][r] -> row = j0+wm*32+mi*16+quad*4+r, col = c0+wn*32+ni*16+l15.
    {
        const size_t base =
            (size_t)(j0 + wm * 32 + quad * 4) * CTX_N + c0 + wn * 32 + l15;
#pragma unroll
        for (int mi = 0; mi < 2; ++mi)
#pragma unroll
            for (int r = 0; r < 4; ++r) {
                const size_t rowb = base + (size_t)(mi * 16 + r) * CTX_N;
#pragma unroll
                for (int ni = 0; ni < 2; ++ni) {
                    const size_t idx = rowb + ni * 16;
                    Rt[idx] = (bf16_t)(acc[mi][ni][r] - (float)Vt[idx]);
                }
            }
    }
}

// ---- K2: out[i][j] = W[i][j] - c * sum_c Kt[i][c]*Rt[j][c]  (4096x4096) ----
// BM=256(i) x BN=128(j), BK=32, 512 threads, 8 waves as 4m x 2n, each 64x64
// out (acc[4][4]). Grid (32,16) = 512 blocks = 2/CU (two streams). L2 tile
// traffic 192 MB (Kt re-read x32, Rt x16). LDS 2 x 24 KB dbuf.
// Staging: unit = 16 rows x 64B (1 KB); A = 16 units, B = 8 units; wave w
// stages A units {w, w+8} + B unit {w} (3 gld16/thread/step). Slot-XOR:
// lane l sources global (row l>>2, seg (l&3)^((l>>2)&3)), LDS dest lane-
// linear; frag read seg = quad^(row&3) -> <=2-way bank alias (free).
// Epilogue BARRIER-FREE: per-fragment W prefetch one mi-block ahead, FMA,
// dword store. Bijective XCD swizzle: same yp (Kt i-slice) -> same XCD.

#define K2_COMPUTE(BSEL)                                                      \
    {                                                                         \
        const bf16_t* bufA = stg + (BSEL) * 12288;                            \
        const bf16_t* bufB = bufA + 8192;                                     \
        const int sgx = (quad ^ (l15 & 3)) * 8;                               \
        bf16x8 af[4], bq[4];                                                  \
        _Pragma("unroll")                                                     \
        for (int mi = 0; mi < 4; ++mi)                                        \
            af[mi] = *(const bf16x8*)(                                        \
                bufA + ((wave >> 1) * 4 + mi) * 512 + l15 * 32 + sgx);        \
        _Pragma("unroll")                                                     \
        for (int ni = 0; ni < 4; ++ni)                                        \
            bq[ni] = *(const bf16x8*)(                                        \
                bufB + ((wave & 1) * 4 + ni) * 512 + l15 * 32 + sgx);         \
        _Pragma("unroll")                                                     \
        for (int mi = 0; mi < 4; ++mi)                                        \
            _Pragma("unroll")                                                 \
            for (int ni = 0; ni < 4; ++ni)                                    \
                acc[mi][ni] = __builtin_amdgcn_mfma_f32_16x16x32_bf16(        \
                    af[mi], bq[ni], acc[mi][ni], 0, 0, 0);                    \
    }

__global__ __launch_bounds__(512, 2) void k2_update(
    const bf16_t* __restrict__ Kt, const bf16_t* __restrict__ Rt,
    const float* __restrict__ W, float* __restrict__ out)
{
    __shared__ __align__(16) bf16_t stg[2 * 12288];  // 2 x 24 KB

    const int tid = threadIdx.x;

    // Bijective XCD swizzle over 512 blocks: id = (yp&7) + 8*xp + 256*(yp>>3).
    const int id = blockIdx.x + 32 * blockIdx.y;
    const int xp = (id >> 3) & 31;
    const int yp = (id & 7) + 8 * (id >> 8);
    const int j0 = xp * 128, i0 = yp * 256;

    const int lane = tid & 63, wave = tid >> 6;
    const int wi = (wave >> 1) * 64, wj = (wave & 1) * 64;
    const int l15 = lane & 15, quad = lane >> 4;

    f32x4 acc[4][4] = {};

    // Staging source (slot-XOR pre-permuted): lane l -> row l>>2, seg
    // (l&3)^((l>>2)&3) within its unit's 64B row window.
    const int rl = lane >> 2;                          // row in unit 0..15
    const int sl = ((lane & 3) ^ (rl & 3)) * 8;        // permuted seg (elems)
    const bf16_t* gA0 = Kt + (size_t)(i0 + wave * 16       + rl) * CTX_N + sl;
    const bf16_t* gA1 = Kt + (size_t)(i0 + wave * 16 + 128 + rl) * CTX_N + sl;
    const bf16_t* gB0 = Rt + (size_t)(j0 + wave * 16       + rl) * CTX_N + sl;

    auto stage = [&](int bsel, int cc) {
        bf16_t* buf = stg + bsel * 12288;
        gld16(gA0 + cc, buf + (size_t)wave * 512 + lane * 8);
        gld16(gA1 + cc, buf + (size_t)(wave + 8) * 512 + lane * 8);
        gld16(gB0 + cc, buf + 8192 + (size_t)wave * 512 + lane * 8);
    };

    // 16 K-tiles of 32. Prologue: tile 0 -> buf0.
    stage(0, 0);
    __syncthreads();
#pragma unroll 1
    for (int t = 1; t <= 13; t += 2) {
        stage(1, t * 32);
        __builtin_amdgcn_sched_barrier(0);
        K2_COMPUTE(0);                  // tile t-1
        __syncthreads();
        stage(0, (t + 1) * 32);
        __builtin_amdgcn_sched_barrier(0);
        K2_COMPUTE(1);                  // tile t
        __syncthreads();
    }
    stage(1, 15 * 32);
    __builtin_amdgcn_sched_barrier(0);
    K2_COMPUTE(0);                      // tile 14
    __syncthreads();
    K2_COMPUTE(1);                      // tile 15

    // ---- Barrier-free direct epilogue ----
    // acc[mi][ni][r] maps to row = i0+wi+mi*16+quad*4+r, col = j0+wj+ni*16+l15.
    const size_t base = (size_t)(i0 + wi + quad * 4) * D_DIM + j0 + wj + l15;
    const float* wp = W + base;
    float*       op = out + base;

    // Prefetch mi=0's 16 W fragments.
    float w0[16], w1[16];
#pragma unroll
    for (int r = 0; r < 4; ++r)
#pragma unroll
        for (int ni = 0; ni < 4; ++ni)
            w0[r * 4 + ni] = wp[(size_t)r * D_DIM + ni * 16];

#pragma unroll
    for (int mi = 0; mi < 4; ++mi) {
        float* wcur = (mi & 1) ? w1 : w0;
        float* wnxt = (mi & 1) ? w0 : w1;
        if (mi < 3) {
#pragma unroll
            for (int r = 0; r < 4; ++r)
#pragma unroll
                for (int ni = 0; ni < 4; ++ni)
                    wnxt[r * 4 + ni] =
                        wp[(size_t)((mi + 1) * 16 + r) * D_DIM + ni * 16];
        }
#pragma unroll
        for (int r = 0; r < 4; ++r)
#pragma unroll
            for (int ni = 0; ni < 4; ++ni)
                op[(size_t)(mi * 16 + r) * D_DIM + ni * 16] =
                    wcur[r * 4 + ni] - UPD_SCALE * acc[mi][ni][r];
    }
}

extern "C" void kernel_launch(void* const* d_in, const int* in_sizes, int n_in,
                              void* d_out, int out_size, void* d_ws, size_t ws_size,
                              hipStream_t stream) {
    const float* W = (const float*)d_in[0];   // (4096, 4096)
    const float* K = (const float*)d_in[1];   // (512, 4096)
    const float* V = (const float*)d_in[2];   // (512, 4096)
    float* out = (float*)d_out;

    char* ws = (char*)d_ws;                    // 48 MB used
    bf16_t* Wt = (bf16_t*)(ws);                            // (4096,4096) W^T
    bf16_t* Kt = (bf16_t*)(ws + (size_t)32 * 1024 * 1024); // (4096,512) K^T
    bf16_t* Kb = (bf16_t*)(ws + (size_t)36 * 1024 * 1024); // (512,4096) K
    bf16_t* Vt = (bf16_t*)(ws + (size_t)40 * 1024 * 1024); // (4096,512) V^T
    bf16_t* Rt = (bf16_t*)(ws + (size_t)44 * 1024 * 1024); // (4096,512) R^T

    t_all      <<<dim3(64, 80), 256, 0, stream>>>(W, K, V, Wt, Kt, Kb, Vt);
    k1_residual<<<dim3(64, 8),  256, 0, stream>>>(Wt, Kb, Vt, Rt);
    k2_update  <<<dim3(32, 16), 512, 0, stream>>>(Kt, Rt, W, out);
}